// Round 3
// baseline (208.978 us; speedup 1.0000x reference)
//
#include <hip/hip_runtime.h>
#include <hip/hip_bf16.h>
#include <math.h>

#define KS 3
#define C_IN 64
#define F_OUT 128
#define NPOS 9
#define HH 128
#define WWID 128
#define NB 16

typedef __attribute__((ext_vector_type(8))) short bf16x8;
typedef __attribute__((ext_vector_type(8))) unsigned short u16x8;
typedef __attribute__((ext_vector_type(4))) float f32x4;

__device__ __forceinline__ unsigned short f2bf(float f) {
  union { float f; unsigned u; } v; v.f = f;
  unsigned u = v.u;
  unsigned r = (u + 0x7FFFu + ((u >> 16) & 1u)) >> 16;  // RNE
  return (unsigned short)r;
}

// ---- Kernel 1: AWt[p][f][c] (bf16) = topk-mask(L) * sign(kern_flat[L]),
// L = ((p*64)+c)*128+f index-aligned across D/gumbel/kern/A (raw reshapes).
__global__ void compute_aw(const float* __restrict__ kern,
                           const float* __restrict__ D,
                           const float* __restrict__ gu,
                           unsigned short* __restrict__ AWt) {
  int t = blockIdx.x * blockDim.x + threadIdx.x;
  if (t >= F_OUT * C_IN) return;
  int base = t * NPOS;
  float pert[NPOS];
#pragma unroll
  for (int n = 0; n < NPOS; ++n) {
    float u = gu[base + n];
    float g = -0.001f * logf(-logf(u + 1e-20f) + 1e-20f);
    pert[n] = D[base + n] + g;
  }
  unsigned mask = 0;
#pragma unroll
  for (int k = 0; k < 4; ++k) {
    int best = 0; float bv = -INFINITY;
#pragma unroll
    for (int n = 0; n < NPOS; ++n) {
      bool taken = (mask >> n) & 1;
      if (!taken && pert[n] > bv) { bv = pert[n]; best = n; }
    }
    mask |= (1u << best);
  }
#pragma unroll
  for (int n = 0; n < NPOS; ++n) {
    int L = base + n;
    float kv = kern[L];
    float s = (kv > 0.f) ? 1.f : ((kv < 0.f) ? -1.f : 0.f);
    float v = ((mask >> n) & 1) ? s : 0.f;
    int f = L & (F_OUT - 1);
    int r = L >> 7;
    int c = r & (C_IN - 1);
    int p = r >> 6;
    AWt[(p * F_OUT + f) * C_IN + c] = f2bf(v);
  }
}

// ---- Kernel 2: x fp32 -> bf16, 8 elems/thread.
__global__ void convert_x(const float* __restrict__ x, unsigned short* __restrict__ xb) {
  long long i = ((long long)blockIdx.x * 256 + threadIdx.x) * 8;
  float4 v0 = *reinterpret_cast<const float4*>(x + i);
  float4 v1 = *reinterpret_cast<const float4*>(x + i + 4);
  u16x8 o;
  o[0] = f2bf(v0.x); o[1] = f2bf(v0.y); o[2] = f2bf(v0.z); o[3] = f2bf(v0.w);
  o[4] = f2bf(v1.x); o[5] = f2bf(v1.y); o[6] = f2bf(v1.z); o[7] = f2bf(v1.w);
  *reinterpret_cast<u16x8*>(xb + i) = o;
}

// ---- Kernel 3: implicit-GEMM conv, MFMA 16x16x32 bf16, NO LDS / NO barriers.
// Block = (n,h) row: M=128 (w) x N=128 (f), K=576. Waves split N (32 f each).
// A-frags read from global bf16 x (L1/L2-hot), B-frags from AWt (L2-hot).
__global__ void conv_gmem(const short* __restrict__ xb,
                          const short* __restrict__ AWt,
                          const float* __restrict__ bias,
                          float* __restrict__ out) {
  int bid = blockIdx.x;
  int wg = (bid & 7) * 256 + (bid >> 3);   // XCD-contiguous (2048 % 8 == 0)
  int n = wg >> 7;
  int h = wg & (HH - 1);

  int lane = threadIdx.x & 63;
  int wave = threadIdx.x >> 6;
  int lr = lane & 15;
  int lg = lane >> 4;
  int f0 = wave * 32;                      // wave's f range

  f32x4 acc[8][2] = {};

#pragma unroll 1
  for (int i = 0; i < KS; ++i) {
    int hh = h + i - 1;
    if ((unsigned)hh >= (unsigned)HH) continue;   // uniform skip at h=0/127
    const short* xr = xb + ((long long)(n * HH + hh) * WWID) * C_IN;
#pragma unroll
    for (int j = 0; j < KS; ++j) {
      int p = i * KS + j;
#pragma unroll
      for (int ch = 0; ch < 2; ++ch) {
        int kc = ch * 32 + lg * 8;
        bf16x8 b0 = *reinterpret_cast<const bf16x8*>(
            AWt + ((p * F_OUT + f0 + lr) * C_IN + kc));
        bf16x8 b1 = *reinterpret_cast<const bf16x8*>(
            AWt + ((p * F_OUT + f0 + 16 + lr) * C_IN + kc));
        bf16x8 a[8];
#pragma unroll
        for (int mf = 0; mf < 8; ++mf) {
          int wq = mf * 16 + lr + j - 1;
          bf16x8 av = {};
          if ((unsigned)wq < (unsigned)WWID)
            av = *reinterpret_cast<const bf16x8*>(xr + (wq * C_IN + kc));
          a[mf] = av;
        }
#pragma unroll
        for (int mf = 0; mf < 8; ++mf) {
          acc[mf][0] = __builtin_amdgcn_mfma_f32_16x16x32_bf16(a[mf], b0, acc[mf][0], 0, 0, 0);
          acc[mf][1] = __builtin_amdgcn_mfma_f32_16x16x32_bf16(a[mf], b1, acc[mf][1], 0, 0, 0);
        }
      }
    }
  }

  long long obase = ((long long)(n * HH + h) * WWID) * F_OUT;
  float bb0 = bias[f0 + lr];
  float bb1 = bias[f0 + 16 + lr];
#pragma unroll
  for (int mf = 0; mf < 8; ++mf) {
#pragma unroll
    for (int r = 0; r < 4; ++r) {
      int w = mf * 16 + lg * 4 + r;
      long long o = obase + (long long)w * F_OUT + f0 + lr;
      out[o]      = fmaxf(acc[mf][0][r] + bb0, 0.f);
      out[o + 16] = fmaxf(acc[mf][1][r] + bb1, 0.f);
    }
  }
}

// ---- Fallback (round-2 kernel, used only if ws too small for bf16 x copy).
__global__ void conv_mfma(const float* __restrict__ x,
                          const short* __restrict__ AWt,
                          const float* __restrict__ bias,
                          float* __restrict__ out) {
  __shared__ __align__(16) char xs[3 * 130 * 128];
  int bid = blockIdx.x;
  int wg = (bid & 7) * 256 + (bid >> 3);
  int n = wg >> 7;
  int h = wg & (HH - 1);
  for (int it = threadIdx.x; it < 3 * 130 * 16; it += 256) {
    int i = it / (130 * 16);
    int rem = it - i * (130 * 16);
    int q = rem >> 4;
    int g = rem & 15;
    int c = g * 4;
    int hh = h + i - 1;
    int wq = q - 1;
    ushort4 v4 = make_ushort4(0, 0, 0, 0);
    if ((unsigned)hh < (unsigned)HH && (unsigned)wq < (unsigned)WWID) {
      const float4 xv = *reinterpret_cast<const float4*>(
          x + (((long long)n * HH + hh) * WWID + wq) * C_IN + c);
      v4.x = f2bf(xv.x); v4.y = f2bf(xv.y); v4.z = f2bf(xv.z); v4.w = f2bf(xv.w);
    }
    int cb = c * 2;
    int off = (i * 130 + q) * 128 + (cb ^ ((q & 7) << 4));
    *reinterpret_cast<ushort4*>(xs + off) = v4;
  }
  __syncthreads();
  int lane = threadIdx.x & 63;
  int wave = threadIdx.x >> 6;
  int m0 = wave * 32;
  int lr = lane & 15;
  int lg = lane >> 4;
  f32x4 acc[2][8] = {};
#pragma unroll 1
  for (int kk = 0; kk < 18; ++kk) {
    int p = kk >> 1, ch = kk & 1;
    int i = p / 3, j = p % 3;
    bf16x8 b[8];
#pragma unroll
    for (int nf = 0; nf < 8; ++nf)
      b[nf] = *reinterpret_cast<const bf16x8*>(
          AWt + ((p * F_OUT + nf * 16 + lr) * C_IN + ch * 32 + lg * 8));
#pragma unroll
    for (int mf = 0; mf < 2; ++mf) {
      int q = m0 + mf * 16 + lr + j;
      int cb = ch * 64 + lg * 16;
      int off = (i * 130 + q) * 128 + (cb ^ ((q & 7) << 4));
      bf16x8 a = *reinterpret_cast<const bf16x8*>(xs + off);
#pragma unroll
      for (int nf = 0; nf < 8; ++nf)
        acc[mf][nf] = __builtin_amdgcn_mfma_f32_16x16x32_bf16(a, b[nf], acc[mf][nf], 0, 0, 0);
    }
  }
  long long obase = (((long long)n * HH + h) * WWID) * F_OUT;
#pragma unroll
  for (int mf = 0; mf < 2; ++mf) {
#pragma unroll
    for (int nf = 0; nf < 8; ++nf) {
      int f = nf * 16 + lr;
      float bb = bias[f];
#pragma unroll
      for (int r = 0; r < 4; ++r) {
        int w = m0 + mf * 16 + lg * 4 + r;
        float v = acc[mf][nf][r] + bb;
        out[obase + (long long)w * F_OUT + f] = fmaxf(v, 0.f);
      }
    }
  }
}

extern "C" void kernel_launch(void* const* d_in, const int* in_sizes, int n_in,
                              void* d_out, int out_size, void* d_ws, size_t ws_size,
                              hipStream_t stream) {
  const float* x    = (const float*)d_in[0];  // (16,128,128,64)
  const float* kern = (const float*)d_in[1];  // (3,3,64,128)
  const float* bias = (const float*)d_in[2];  // (128,)
  const float* D    = (const float*)d_in[3];  // (3,3,64,128)
  const float* gu   = (const float*)d_in[4];  // (1,128,64,9)

  const size_t xbytes = (size_t)NB * HH * WWID * C_IN * 2;          // 32 MiB
  const size_t awbytes = (size_t)NPOS * F_OUT * C_IN * 2;           // 144 KiB
  bool big = ws_size >= xbytes + awbytes;

  unsigned short* xb  = (unsigned short*)d_ws;
  unsigned short* AWt = big ? (unsigned short*)((char*)d_ws + xbytes)
                            : (unsigned short*)d_ws;

  compute_aw<<<(F_OUT * C_IN + 255) / 256, 256, 0, stream>>>(kern, D, gu, AWt);

  if (big) {
    long long nel = (long long)NB * HH * WWID * C_IN;               // 16.78M
    convert_x<<<(int)(nel / (256 * 8)), 256, 0, stream>>>(x, xb);
    conv_gmem<<<NB * HH, 256, 0, stream>>>((const short*)xb, (const short*)AWt,
                                           bias, (float*)d_out);
  } else {
    conv_mfma<<<NB * HH, 256, 0, stream>>>(x, (const short*)AWt, bias, (float*)d_out);
  }
}

// Round 4
// 124.323 us; speedup vs baseline: 1.6809x; 1.6809x over previous
//
#include <hip/hip_runtime.h>
#include <hip/hip_bf16.h>
#include <math.h>

#define KS 3
#define C_IN 64
#define F_OUT 128
#define NPOS 9
#define HH 128
#define WWID 128
#define NB 16

typedef __attribute__((ext_vector_type(8))) short bf16x8;
typedef __attribute__((ext_vector_type(4))) float f32x4;

__device__ __forceinline__ unsigned short f2bf(float f) {
  union { float f; unsigned u; } v; v.f = f;
  unsigned u = v.u;
  return (unsigned short)((u + 0x7FFFu + ((u >> 16) & 1u)) >> 16);  // RNE
}

__device__ __forceinline__ unsigned cvtpk(float lo, float hi) {
  unsigned r;
  asm("v_cvt_pk_bf16_f32 %0, %1, %2" : "=v"(r) : "v"(lo), "v"(hi));
  return r;
}

__device__ __forceinline__ bf16x8 pack8(float4 v0, float4 v1) {
  union { unsigned u[4]; bf16x8 v; } r;
  r.u[0] = cvtpk(v0.x, v0.y);
  r.u[1] = cvtpk(v0.z, v0.w);
  r.u[2] = cvtpk(v1.x, v1.y);
  r.u[3] = cvtpk(v1.z, v1.w);
  return r.v;
}

// ---- Kernel 1: swizzled AW.  Element (p,f,c) of A*sign(kern) (bf16) goes to
// chunk-swizzled index ((p*128+f)*8 + ((c>>3) ^ (f&7)))*8 + (c&7), so that the
// conv kernel's linear LDS copy + swizzled ds_read_b128 is bank-conflict-free.
__global__ void compute_aw(const float* __restrict__ kern,
                           const float* __restrict__ D,
                           const float* __restrict__ gu,
                           unsigned short* __restrict__ AWsw) {
  int t = blockIdx.x * blockDim.x + threadIdx.x;
  if (t >= F_OUT * C_IN) return;
  int base = t * NPOS;
  float pert[NPOS];
#pragma unroll
  for (int n = 0; n < NPOS; ++n) {
    float u = gu[base + n];
    float g = -0.001f * logf(-logf(u + 1e-20f) + 1e-20f);
    pert[n] = D[base + n] + g;
  }
  unsigned mask = 0;
#pragma unroll
  for (int k = 0; k < 4; ++k) {
    int best = 0; float bv = -INFINITY;
#pragma unroll
    for (int n = 0; n < NPOS; ++n) {
      bool taken = (mask >> n) & 1;
      if (!taken && pert[n] > bv) { bv = pert[n]; best = n; }
    }
    mask |= (1u << best);
  }
#pragma unroll
  for (int n = 0; n < NPOS; ++n) {
    int L = base + n;
    float kv = kern[L];
    float s = (kv > 0.f) ? 1.f : ((kv < 0.f) ? -1.f : 0.f);
    float v = ((mask >> n) & 1) ? s : 0.f;
    int f = L & (F_OUT - 1);
    int r = L >> 7;
    int c = r & (C_IN - 1);
    int p = r >> 6;
    int g = c >> 3;
    int idx = ((p * F_OUT + f) * 8 + (g ^ (f & 7))) * 8 + (c & 7);
    AWsw[idx] = f2bf(v);
  }
}

// ---- Kernel 2: persistent implicit-GEMM conv.
// Grid 256 (1 block/CU), 512 threads (8 waves). B = full AWt in LDS (144 KiB,
// swizzled, staged once). Each block owns an 8-row strip of one image; waves =
// 4 rows x 2 M-halves; per wave mf=4 (M=64), nf=8 (N=128), K=576.
// A streams from global fp32 -> cvt_pk bf16 per fragment (no convert pass).
__global__ __launch_bounds__(512, 2)
void conv_persist(const float* __restrict__ x,
                  const unsigned short* __restrict__ AWsw,
                  const float* __restrict__ bias,
                  float* __restrict__ out) {
  __shared__ __align__(16) short Bs[NPOS * F_OUT * C_IN];  // 144 KiB

  int tid = threadIdx.x;
  int lane = tid & 63;
  int wave = tid >> 6;
  int lr = lane & 15;
  int lg = lane >> 4;

  // stage B linearly: 9216 chunks of 16 B, 18 per thread.
#pragma unroll
  for (int t = 0; t < 18; ++t) {
    int ci = t * 512 + tid;
    *reinterpret_cast<bf16x8*>(Bs + ci * 8) =
        *reinterpret_cast<const bf16x8*>(AWsw + ci * 8);
  }
  __syncthreads();

  int n = blockIdx.x >> 4;
  int h0 = (blockIdx.x & 15) * 8;
  int m0 = (wave & 1) * 64;
  int rowsub = wave >> 1;

#pragma unroll 1
  for (int rr = 0; rr < 2; ++rr) {
    int h = h0 + rr * 4 + rowsub;
    f32x4 acc[4][8] = {};

#pragma unroll 1
    for (int i = 0; i < KS; ++i) {
      int hh = h + i - 1;
      if ((unsigned)hh >= (unsigned)HH) continue;   // wave-uniform skip
      const float* xr = x + ((long long)(n * HH + hh)) * WWID * C_IN;
#pragma unroll
      for (int j = 0; j < KS; ++j) {
#pragma unroll
        for (int ch = 0; ch < 2; ++ch) {
          int p = i * KS + j;
          int g = ch * 4 + lg;                       // 8-channel chunk id
          bf16x8 b[8];
#pragma unroll
          for (int nf = 0; nf < 8; ++nf) {
            int f = nf * 16 + lr;
            int slot = (p * F_OUT + f) * 8 + (g ^ (f & 7));
            b[nf] = *reinterpret_cast<const bf16x8*>(Bs + slot * 8);
          }
          bf16x8 a[4];
#pragma unroll
          for (int mfi = 0; mfi < 4; ++mfi) {
            int px = m0 + mfi * 16 + lr + j - 1;
            float4 v0 = make_float4(0.f, 0.f, 0.f, 0.f);
            float4 v1 = make_float4(0.f, 0.f, 0.f, 0.f);
            if ((unsigned)px < (unsigned)WWID) {
              const float* ap = xr + px * C_IN + g * 8;
              v0 = *reinterpret_cast<const float4*>(ap);
              v1 = *reinterpret_cast<const float4*>(ap + 4);
            }
            a[mfi] = pack8(v0, v1);
          }
#pragma unroll
          for (int mfi = 0; mfi < 4; ++mfi)
#pragma unroll
            for (int nf = 0; nf < 8; ++nf)
              acc[mfi][nf] = __builtin_amdgcn_mfma_f32_16x16x32_bf16(
                  a[mfi], b[nf], acc[mfi][nf], 0, 0, 0);
        }
      }
    }

    long long ob = ((long long)(n * HH + h)) * WWID * F_OUT;
#pragma unroll
    for (int nf = 0; nf < 8; ++nf) {
      float bb = bias[nf * 16 + lr];
#pragma unroll
      for (int mfi = 0; mfi < 4; ++mfi) {
#pragma unroll
        for (int r = 0; r < 4; ++r) {
          int w = m0 + mfi * 16 + lg * 4 + r;
          out[ob + (long long)w * F_OUT + nf * 16 + lr] =
              fmaxf(acc[mfi][nf][r] + bb, 0.f);
        }
      }
    }
  }
}

extern "C" void kernel_launch(void* const* d_in, const int* in_sizes, int n_in,
                              void* d_out, int out_size, void* d_ws, size_t ws_size,
                              hipStream_t stream) {
  const float* x    = (const float*)d_in[0];  // (16,128,128,64)
  const float* kern = (const float*)d_in[1];  // (3,3,64,128)
  const float* bias = (const float*)d_in[2];  // (128,)
  const float* D    = (const float*)d_in[3];  // (3,3,64,128)
  const float* gu   = (const float*)d_in[4];  // (1,128,64,9)

  unsigned short* AWsw = (unsigned short*)d_ws;  // 73728 bf16 = 144 KiB

  compute_aw<<<(F_OUT * C_IN + 255) / 256, 256, 0, stream>>>(kern, D, gu, AWsw);

  conv_persist<<<NB * (HH / 8), 512, 0, stream>>>(x, AWsw, bias, (float*)d_out);
}

// Round 5
// 122.469 us; speedup vs baseline: 1.7064x; 1.0151x over previous
//
#include <hip/hip_runtime.h>
#include <hip/hip_bf16.h>
#include <math.h>

#define KS 3
#define C_IN 64
#define F_OUT 128
#define NPOS 9
#define HH 128
#define WWID 128
#define NB 16

typedef __attribute__((ext_vector_type(8))) short bf16x8;
typedef __attribute__((ext_vector_type(8))) unsigned short u16x8;
typedef __attribute__((ext_vector_type(4))) float f32x4;

__device__ __forceinline__ unsigned short f2bf(float f) {
  union { float f; unsigned u; } v; v.f = f;
  unsigned u = v.u;
  return (unsigned short)((u + 0x7FFFu + ((u >> 16) & 1u)) >> 16);  // RNE
}

// ---- Kernel 1: AW (bf16, {-1,0,1}) in ch-phased chunk-swizzled layout:
// element (p,f,c): ch=c>>5, gl=(c>>3)&3, ps=(gl+((f&15)>>1))&3,
// off = (((ch*9+p)*128+f)*4+ps)*8 + (c&7).  Linear LDS copy of a ch-slice +
// swizzled ds_read_b128 is then 2-way-max bank aliased (free).
__global__ void compute_aw(const float* __restrict__ kern,
                           const float* __restrict__ D,
                           const float* __restrict__ gu,
                           unsigned short* __restrict__ AWsw) {
  int t = blockIdx.x * blockDim.x + threadIdx.x;
  if (t >= F_OUT * C_IN) return;
  int base = t * NPOS;
  float pert[NPOS];
#pragma unroll
  for (int n = 0; n < NPOS; ++n) {
    float u = gu[base + n];
    float g = -0.001f * logf(-logf(u + 1e-20f) + 1e-20f);
    pert[n] = D[base + n] + g;
  }
  unsigned mask = 0;
#pragma unroll
  for (int k = 0; k < 4; ++k) {
    int best = 0; float bv = -INFINITY;
#pragma unroll
    for (int n = 0; n < NPOS; ++n) {
      bool taken = (mask >> n) & 1;
      if (!taken && pert[n] > bv) { bv = pert[n]; best = n; }
    }
    mask |= (1u << best);
  }
#pragma unroll
  for (int n = 0; n < NPOS; ++n) {
    int L = base + n;
    float kv = kern[L];
    float s = (kv > 0.f) ? 1.f : ((kv < 0.f) ? -1.f : 0.f);
    float v = ((mask >> n) & 1) ? s : 0.f;
    int f = L & (F_OUT - 1);
    int r = L >> 7;
    int c = r & (C_IN - 1);
    int p = r >> 6;
    int ch = c >> 5;
    int gl = (c >> 3) & 3;
    int ps = (gl + ((f & 15) >> 1)) & 3;
    int off = (((ch * NPOS + p) * F_OUT + f) * 4 + ps) * 8 + (c & 7);
    AWsw[off] = f2bf(v);
  }
}

// ---- Kernel 2: x fp32 -> bf16, 8 elems/thread.
__global__ void convert_x(const float* __restrict__ x, unsigned short* __restrict__ xb) {
  long long i = ((long long)blockIdx.x * 256 + threadIdx.x) * 8;
  float4 v0 = *reinterpret_cast<const float4*>(x + i);
  float4 v1 = *reinterpret_cast<const float4*>(x + i + 4);
  u16x8 o;
  o[0] = f2bf(v0.x); o[1] = f2bf(v0.y); o[2] = f2bf(v0.z); o[3] = f2bf(v0.w);
  o[4] = f2bf(v1.x); o[5] = f2bf(v1.y); o[6] = f2bf(v1.z); o[7] = f2bf(v1.w);
  *reinterpret_cast<u16x8*>(xb + i) = o;
}

// ---- Kernel 3: implicit-GEMM conv. Block = 2-row strip, 512 thr / 8 waves,
// wave tile M=64 x N=64 (mf=4, nf=4, acc 64 regs). B staged in LDS in two
// 72 KiB ch-phases -> 2 blocks/CU, 4 waves/SIMD. A (bf16 x) from global.
__global__ __launch_bounds__(512, 4)
void conv_strip(const unsigned short* __restrict__ xb,
                const unsigned short* __restrict__ AWsw,
                const float* __restrict__ bias,
                float* __restrict__ out) {
  __shared__ __align__(16) unsigned short Bs[NPOS * F_OUT * 32];  // 72 KiB

  int tid = threadIdx.x;
  int lane = tid & 63, wave = tid >> 6;
  int lr = lane & 15, lg = lane >> 4;

  int bid = blockIdx.x;
  int wg = (bid & 7) * 128 + (bid >> 3);   // XCD-contiguous (1024 % 8 == 0)
  int n = wg >> 6;
  int strip = wg & 63;
  int h = strip * 2 + (wave >> 2);         // each wave owns one row
  int m0 = (wave & 1) * 64;                // M-half
  int f0 = ((wave >> 1) & 1) * 64;         // N-half

  int ps = (lg + (lr >> 1)) & 3;
  int bbase = (f0 + lr) * 64 + ps * 16;    // lane byte offset inside a p-block

  const unsigned short* xim = xb + ((long long)n * HH) * WWID * C_IN;

  f32x4 acc[4][4] = {};

  for (int ch = 0; ch < 2; ++ch) {
    if (ch) __syncthreads();
    // stage ch-slice of B (73728 B) linearly: 16 B x 512 thr x 9
#pragma unroll
    for (int k = 0; k < 9; ++k) {
      int ci = k * 512 + tid;
      *reinterpret_cast<bf16x8*>(Bs + ci * 8) =
          *reinterpret_cast<const bf16x8*>(AWsw + ch * (NPOS * F_OUT * 32) + ci * 8);
    }
    __syncthreads();

#pragma unroll
    for (int i = 0; i < KS; ++i) {
      int hh = h + i - 1;
      if ((unsigned)hh >= (unsigned)HH) continue;   // wave-uniform skip
      const unsigned short* xr =
          xim + (long long)hh * WWID * C_IN + ch * 32 + lg * 8;
#pragma unroll
      for (int j = 0; j < KS; ++j) {
        int p = i * KS + j;
        const char* bp = (const char*)Bs + p * 8192 + bbase;
        bf16x8 b[4];
#pragma unroll
        for (int nf = 0; nf < 4; ++nf)
          b[nf] = *reinterpret_cast<const bf16x8*>(bp + nf * 1024);
#pragma unroll
        for (int mfi = 0; mfi < 4; ++mfi) {
          int px = m0 + mfi * 16 + lr + j - 1;
          bf16x8 a = {};
          if ((unsigned)px < (unsigned)WWID)
            a = *reinterpret_cast<const bf16x8*>(xr + (long long)px * C_IN);
#pragma unroll
          for (int nf = 0; nf < 4; ++nf)
            acc[mfi][nf] = __builtin_amdgcn_mfma_f32_16x16x32_bf16(
                a, b[nf], acc[mfi][nf], 0, 0, 0);
        }
      }
    }
  }

  float bi[4];
#pragma unroll
  for (int nf = 0; nf < 4; ++nf) bi[nf] = bias[f0 + nf * 16 + lr];
  long long ob = (((long long)n * HH + h) * WWID) * F_OUT + f0 + lr;
#pragma unroll
  for (int mfi = 0; mfi < 4; ++mfi) {
#pragma unroll
    for (int r = 0; r < 4; ++r) {
      int w = m0 + mfi * 16 + lg * 4 + r;
      float* op = out + ob + (long long)w * F_OUT;
#pragma unroll
      for (int nf = 0; nf < 4; ++nf)       // nf innermost: 4x64B contiguous
        op[nf * 16] = fmaxf(acc[mfi][nf][r] + bi[nf], 0.f);
    }
  }
}

extern "C" void kernel_launch(void* const* d_in, const int* in_sizes, int n_in,
                              void* d_out, int out_size, void* d_ws, size_t ws_size,
                              hipStream_t stream) {
  const float* x    = (const float*)d_in[0];  // (16,128,128,64)
  const float* kern = (const float*)d_in[1];  // (3,3,64,128)
  const float* bias = (const float*)d_in[2];  // (128,)
  const float* D    = (const float*)d_in[3];  // (3,3,64,128)
  const float* gu   = (const float*)d_in[4];  // (1,128,64,9)

  const size_t xbytes = (size_t)NB * HH * WWID * C_IN * 2;  // 32 MiB
  unsigned short* xb   = (unsigned short*)d_ws;
  unsigned short* AWsw = (unsigned short*)((char*)d_ws + xbytes);  // 144 KiB

  compute_aw<<<(F_OUT * C_IN + 255) / 256, 256, 0, stream>>>(kern, D, gu, AWsw);

  long long nel = (long long)NB * HH * WWID * C_IN;
  convert_x<<<(int)(nel / (256 * 8)), 256, 0, stream>>>(x, xb);

  conv_strip<<<NB * (HH / 2), 512, 0, stream>>>(xb, AWsw, bias, (float*)d_out);
}

// Round 6
// 61.306 us; speedup vs baseline: 3.4087x; 1.9977x over previous
//
#include <hip/hip_runtime.h>
#include <hip/hip_bf16.h>
#include <math.h>

#define KS 3
#define C_IN 64
#define F_OUT 128
#define NPOS 9
#define HH 128
#define WWID 128
#define NB 16

typedef __attribute__((ext_vector_type(8))) short bf16x8;
typedef __attribute__((ext_vector_type(4))) float f32x4;

__device__ __forceinline__ unsigned short f2bf(float f) {
  union { float f; unsigned u; } v; v.f = f;
  unsigned u = v.u;
  return (unsigned short)((u + 0x7FFFu + ((u >> 16) & 1u)) >> 16);  // RNE
}
__device__ __forceinline__ unsigned cvtpk(float lo, float hi) {
  unsigned r;
  asm("v_cvt_pk_bf16_f32 %0, %1, %2" : "=v"(r) : "v"(lo), "v"(hi));
  return r;
}
__device__ __forceinline__ bf16x8 pack8(float4 v0, float4 v1) {
  union { unsigned u[4]; bf16x8 v; } r;
  r.u[0] = cvtpk(v0.x, v0.y); r.u[1] = cvtpk(v0.z, v0.w);
  r.u[2] = cvtpk(v1.x, v1.y); r.u[3] = cvtpk(v1.z, v1.w);
  return r.v;
}

// ---- Kernel 1: AW (bf16 in {-1,0,1}) in phase-sliced swizzled layout.
// Element (p,f,c): ch=c>>5, fh=f>>6, fl=f&63, gl=(c>>3)&3,
// ps=(gl+((f&15)>>1))&3 ->
// off = ((((ch*2+fh)*9+p)*64+fl)*4+ps)*8 + (c&7).
// Each (ch,fh) phase slice is 18432 contiguous elems (36 KiB): linear LDS
// copy + the conv kernel's ps-swizzled ds_read_b128 is conflict-free.
__global__ void compute_aw(const float* __restrict__ kern,
                           const float* __restrict__ D,
                           const float* __restrict__ gu,
                           unsigned short* __restrict__ AWsw) {
  int t = blockIdx.x * blockDim.x + threadIdx.x;
  if (t >= F_OUT * C_IN) return;
  int base = t * NPOS;
  float pert[NPOS];
#pragma unroll
  for (int n = 0; n < NPOS; ++n) {
    float u = gu[base + n];
    float g = -0.001f * logf(-logf(u + 1e-20f) + 1e-20f);
    pert[n] = D[base + n] + g;
  }
  unsigned mask = 0;
#pragma unroll
  for (int k = 0; k < 4; ++k) {
    int best = 0; float bv = -INFINITY;
#pragma unroll
    for (int n = 0; n < NPOS; ++n) {
      bool taken = (mask >> n) & 1;
      if (!taken && pert[n] > bv) { bv = pert[n]; best = n; }
    }
    mask |= (1u << best);
  }
#pragma unroll
  for (int n = 0; n < NPOS; ++n) {
    int L = base + n;
    float kv = kern[L];
    float s = (kv > 0.f) ? 1.f : ((kv < 0.f) ? -1.f : 0.f);
    float v = ((mask >> n) & 1) ? s : 0.f;
    int f = L & (F_OUT - 1);
    int r = L >> 7;
    int c = r & (C_IN - 1);
    int p = r >> 6;
    int ch = c >> 5, gl = (c >> 3) & 3, fh = f >> 6, fl = f & 63;
    int ps = (gl + ((f & 15) >> 1)) & 3;
    int off = ((((ch * 2 + fh) * NPOS + p) * 64 + fl) * 4 + ps) * 8 + (c & 7);
    AWsw[off] = f2bf(v);
  }
}

// ---- Kernel 2: fused implicit-GEMM conv, all MFMA operands LDS-resident.
// Block = 4 output rows (M=512) x F=128, 8 waves, wave tile 64x128.
// A: 6 input rows x 130 px (zero edges) x 64ch bf16, staged once from fp32 x
//    (cvt_pk), XOR-swizzled slot = c8 ^ (px&7).
// B: 4 phases (ch,fh) of 36 KiB, T14 reg-prefetched during prior compute.
__global__ __launch_bounds__(512, 2)
void conv_fused(const float* __restrict__ x,
                const unsigned short* __restrict__ AWsw,
                const float* __restrict__ bias,
                float* __restrict__ out) {
  __shared__ __align__(16) unsigned short As[6 * 130 * 64];   // 99840 B
  __shared__ __align__(16) unsigned short Bs[NPOS * 64 * 32]; // 36864 B

  int tid = threadIdx.x;
  int lane = tid & 63, wave = tid >> 6;
  int lr = lane & 15, lg = lane >> 4;

  int bid = blockIdx.x;
  int wg = (bid & 7) * 64 + (bid >> 3);   // XCD-contiguous (512 % 8 == 0)
  int n = wg >> 5;
  int h0 = (wg & 31) * 4;

  // issue B phase-0 loads early (latency hides under memset/A-stage)
  bf16x8 pre[5];
  int cid4 = 4 * 512 + tid;
#pragma unroll
  for (int t = 0; t < 4; ++t)
    pre[t] = *reinterpret_cast<const bf16x8*>(AWsw + (t * 512 + tid) * 8);
  if (cid4 < 2304)
    pre[4] = *reinterpret_cast<const bf16x8*>(AWsw + cid4 * 8);

  // memset A (covers pad px and out-of-image rows)
  bf16x8 z = {};
  for (int t = tid; t < 6 * 130 * 8; t += 512)
    *reinterpret_cast<bf16x8*>(As + t * 8) = z;
  __syncthreads();

  // stage A: fp32 -> bf16, swizzled ds_write
  const float* xim = x + ((long long)n * HH) * WWID * C_IN;
  for (int r = 0; r < 6; ++r) {
    int hh = h0 - 1 + r;
    if ((unsigned)hh >= (unsigned)HH) continue;   // block-uniform
    const float* xrow = xim + (long long)hh * WWID * C_IN;
#pragma unroll
    for (int t2 = 0; t2 < 2; ++t2) {
      int cid = t2 * 512 + tid;        // 1024 chunks: px(0..127) x c8(0..7)
      int px = cid >> 3, c8 = cid & 7;
      const float* sp = xrow + px * C_IN + c8 * 8;
      float4 v0 = *reinterpret_cast<const float4*>(sp);
      float4 v1 = *reinterpret_cast<const float4*>(sp + 4);
      int pp = px + 1;
      int slot = c8 ^ (pp & 7);
      *reinterpret_cast<bf16x8*>(As + (r * 1040 + pp * 8 + slot) * 8) = pack8(v0, v1);
    }
  }
  // write B phase 0
#pragma unroll
  for (int t = 0; t < 4; ++t)
    *reinterpret_cast<bf16x8*>(Bs + (t * 512 + tid) * 8) = pre[t];
  if (cid4 < 2304)
    *reinterpret_cast<bf16x8*>(Bs + cid4 * 8) = pre[4];
  __syncthreads();

  f32x4 acc[4][8] = {};
  int bb0 = lr * 64 + (((lg + (lr >> 1)) & 3) << 4);
  int w0 = (wave & 1) * 64;
  int ro = wave >> 1;
  const char* Asb = (const char*)As;
  const char* Bsb = (const char*)Bs;

#pragma unroll
  for (int phid = 0; phid < 4; ++phid) {
    const int ch = phid >> 1, fh = phid & 1;
    // prefetch next B slice into regs (consumed after the barrier)
    if (phid < 3) {
#pragma unroll
      for (int t = 0; t < 4; ++t)
        pre[t] = *reinterpret_cast<const bf16x8*>(
            AWsw + ((phid + 1) * 2304 + t * 512 + tid) * 8);
      if (cid4 < 2304)
        pre[4] = *reinterpret_cast<const bf16x8*>(
            AWsw + ((phid + 1) * 2304 + cid4) * 8);
    }
    // compute: 9 positions x (4 a + 4 b ds_read_b128 + 16 MFMA)
#pragma unroll
    for (int p = 0; p < NPOS; ++p) {
      const int i = p / 3, j = p % 3;
      bf16x8 b[4];
#pragma unroll
      for (int nf = 0; nf < 4; ++nf)
        b[nf] = *reinterpret_cast<const bf16x8*>(Bsb + p * 4096 + nf * 1024 + bb0);
      int pxb = w0 + lr + j;
      int slot = (ch * 4 + lg) ^ (pxb & 7);
      int abase = (ro + i) * 16640 + pxb * 128 + slot * 16;
      bf16x8 a[4];
#pragma unroll
      for (int mfi = 0; mfi < 4; ++mfi)
        a[mfi] = *reinterpret_cast<const bf16x8*>(Asb + abase + mfi * 2048);
#pragma unroll
      for (int mfi = 0; mfi < 4; ++mfi)
#pragma unroll
        for (int nf = 0; nf < 4; ++nf)
          acc[mfi][fh * 4 + nf] = __builtin_amdgcn_mfma_f32_16x16x32_bf16(
              a[mfi], b[nf], acc[mfi][fh * 4 + nf], 0, 0, 0);
    }
    if (phid < 3) {
      __syncthreads();                 // all waves done reading Bs
#pragma unroll
      for (int t = 0; t < 4; ++t)
        *reinterpret_cast<bf16x8*>(Bs + (t * 512 + tid) * 8) = pre[t];
      if (cid4 < 2304)
        *reinterpret_cast<bf16x8*>(Bs + cid4 * 8) = pre[4];
      __syncthreads();                 // next slice ready
    }
  }

  // epilogue: D col=lr (f), row=lg*4+r (w); nf innermost -> 8x64B = 512B/f-line
  float bi[8];
#pragma unroll
  for (int nf = 0; nf < 8; ++nf) bi[nf] = bias[nf * 16 + lr];
  int ho = h0 + ro;
  long long ob = ((long long)(n * HH + ho)) * WWID * F_OUT + lr;
#pragma unroll
  for (int mfi = 0; mfi < 4; ++mfi) {
#pragma unroll
    for (int r = 0; r < 4; ++r) {
      int w = w0 + mfi * 16 + lg * 4 + r;
      float* op = out + ob + (long long)w * F_OUT;
#pragma unroll
      for (int nf = 0; nf < 8; ++nf)
        op[nf * 16] = fmaxf(acc[mfi][nf][r] + bi[nf], 0.f);
    }
  }
}

extern "C" void kernel_launch(void* const* d_in, const int* in_sizes, int n_in,
                              void* d_out, int out_size, void* d_ws, size_t ws_size,
                              hipStream_t stream) {
  const float* x    = (const float*)d_in[0];  // (16,128,128,64)
  const float* kern = (const float*)d_in[1];  // (3,3,64,128)
  const float* bias = (const float*)d_in[2];  // (128,)
  const float* D    = (const float*)d_in[3];  // (3,3,64,128)
  const float* gu   = (const float*)d_in[4];  // (1,128,64,9)

  unsigned short* AWsw = (unsigned short*)d_ws;  // 73728 bf16 = 144 KiB

  compute_aw<<<(F_OUT * C_IN + 255) / 256, 256, 0, stream>>>(kern, D, gu, AWsw);

  conv_fused<<<NB * (HH / 4), 512, 0, stream>>>(x, AWsw, bias, (float*)d_out);
}